// Round 2
// 283.439 us; speedup vs baseline: 1.1161x; 1.1161x over previous
//
#include <hip/hip_runtime.h>
#include <stdint.h>

// Problem constants (fixed by reference setup_inputs)
constexpr int N = 65536, K = 512, F = 512;
constexpr float ASCALE = 127.0f / 3.0f;   // activation scale (fixed bound 3.0)

typedef short frag8 __attribute__((ext_vector_type(8)));   // 8 bf16 = 4 VGPRs
typedef float floatx4 __attribute__((ext_vector_type(4))); // MFMA C/D

// round-half-even, clip to [-127,127], truncate fp32->bf16 (exact for ints <= 127)
__device__ __forceinline__ unsigned short quant_bf16(float v, float s) {
    float q = rintf(v * s);
    q = fminf(fmaxf(q, -127.0f), 127.0f);
    union { float f; unsigned int u; } cvt; cvt.f = q;
    return (unsigned short)(cvt.u >> 16);
}

// quantize 8 consecutive floats -> packed 8x bf16 (uint4)
__device__ __forceinline__ uint4 quant8(const float4& a, const float4& b) {
    unsigned int q0 = quant_bf16(a.x, ASCALE), q1 = quant_bf16(a.y, ASCALE);
    unsigned int q2 = quant_bf16(a.z, ASCALE), q3 = quant_bf16(a.w, ASCALE);
    unsigned int q4 = quant_bf16(b.x, ASCALE), q5 = quant_bf16(b.y, ASCALE);
    unsigned int q6 = quant_bf16(b.z, ASCALE), q7 = quant_bf16(b.w, ASCALE);
    uint4 r;
    r.x = q0 | (q1 << 16); r.y = q2 | (q3 << 16);
    r.z = q4 | (q5 << 16); r.w = q6 | (q7 << 16);
    return r;
}

// --- Phase 1: per-output-channel weight quant -> wT[f][k] (bf16), dscale[f] ---
// 16 blocks x 512 threads. Block owns 32 f-cols. Thread (fl = t&31, kc = t>>5)
// holds rows kc*32..+32 of column f0+fl in registers (coalesced loads across fl).
// LDS transpose buffer gives fully-coalesced 16B writes of wT.
__global__ __launch_bounds__(512)
void quant_w_kernel(const float* __restrict__ kern,
                    unsigned short* __restrict__ wT,
                    float* __restrict__ dscale) {
    constexpr int TF = 32;          // f-cols per block
    constexpr int RK = 32;          // k-rows per thread (512 / 16 partitions)
    constexpr int LDQ = K + 8;      // pad: even bank spread on 16B LDS writes
    __shared__ float pmax[16][TF];
    __shared__ float wscl[TF];
    __shared__ unsigned short q_t[TF * LDQ];   // 32 f x 512 k (+pad) bf16

    int t = threadIdx.x;
    int fl = t & 31;
    int kc = t >> 5;                // 0..15
    int f0 = blockIdx.x * TF;
    int f = f0 + fl;

    // coalesced register-resident column chunk
    float v[RK];
    const float* kp = kern + (size_t)(kc * RK) * F + f;
    #pragma unroll
    for (int j = 0; j < RK; ++j) v[j] = kp[(size_t)j * F];

    float mx = 0.0f;
    #pragma unroll
    for (int j = 0; j < RK; ++j) mx = fmaxf(mx, fabsf(v[j]));
    pmax[kc][fl] = mx;
    __syncthreads();

    if (t < TF) {
        float m = 0.0f;
        #pragma unroll
        for (int p = 0; p < 16; ++p) m = fmaxf(m, pmax[p][t]);
        m = fmaxf(m, 1e-7f);
        wscl[t] = 127.0f / m;
        dscale[f0 + t] = 3.0f * m / 16129.0f;   // 1/(a_scale*w_scale)
    }
    __syncthreads();

    float ws = wscl[fl];
    // quantize from regs -> LDS transpose tile, 16B per write
    #pragma unroll
    for (int i = 0; i < RK / 8; ++i) {
        unsigned int q0 = quant_bf16(v[i*8+0], ws), q1 = quant_bf16(v[i*8+1], ws);
        unsigned int q2 = quant_bf16(v[i*8+2], ws), q3 = quant_bf16(v[i*8+3], ws);
        unsigned int q4 = quant_bf16(v[i*8+4], ws), q5 = quant_bf16(v[i*8+5], ws);
        unsigned int q6 = quant_bf16(v[i*8+6], ws), q7 = quant_bf16(v[i*8+7], ws);
        uint4 pk;
        pk.x = q0 | (q1 << 16); pk.y = q2 | (q3 << 16);
        pk.z = q4 | (q5 << 16); pk.w = q6 | (q7 << 16);
        *(uint4*)&q_t[fl * LDQ + kc * RK + i * 8] = pk;
    }
    __syncthreads();

    // fully-coalesced writeout: chunk C covers 8 elems; wave writes 1KB contiguous
    #pragma unroll
    for (int pass = 0; pass < (TF * K / 8) / 512; ++pass) {   // 4 passes
        int C = pass * 512 + t;
        int r = C >> 6;            // row in [0,32)
        int c = C & 63;            // 16B chunk within row
        *(uint4*)&wT[(size_t)(f0 + r) * K + c * 8] =
            *(const uint4*)&q_t[r * LDQ + c * 8];
    }
}

// --- Phase 2: fused quant-x + bf16 MFMA GEMM + dequant + bias ---
// 1024 blocks x 512 threads (8 waves). BM=64, BN=F=512, BK=128 (4 K-steps,
// 4 barriers/block total). Wave w owns cols [w*64, w*64+64): 4x4 acc tiles.
// B-fragments load DIRECTLY from L2-resident wT (reg double-buffered, one
// k-subtile ahead) -- no LDS, no barrier dependency for B. Only x is staged
// through LDS (needs quant + 8-wave sharing), double-buffered, with the next
// step's x issued at the top of the current step and written at the bottom.
__global__ __launch_bounds__(512)
void gemm_kernel(const float* __restrict__ x,
                 const unsigned short* __restrict__ wT,
                 const float* __restrict__ dscale,
                 const float* __restrict__ bias,
                 float* __restrict__ out) {
    constexpr int BM = 64, BK = 128, NSTEP = K / BK;   // 4 steps
    constexpr int LDA = BK + 8;                        // 136: 16B-aligned rows, even bank spread
    __shared__ unsigned short As[2][BM * LDA];         // 2 x 17408 B

    const int t = threadIdx.x;
    const int blk = blockIdx.x;
    const int lane = t & 63;
    const int wave = t >> 6;     // 0..7
    const int m16 = lane & 15;
    const int quad = lane >> 4;

    floatx4 acc[4][4];
    #pragma unroll
    for (int i = 0; i < 4; ++i)
        #pragma unroll
        for (int j = 0; j < 4; ++j)
            acc[i][j] = (floatx4){0.f, 0.f, 0.f, 0.f};

    // x staging: thread -> row t>>3, cols (t&7)*8 + {0..7} and +64..71 (2x 8-elem groups)
    const int arow = t >> 3;
    const int acol = (t & 7) * 8;
    const float* xp = x + (size_t)(blk * BM + arow) * K + acol;

    // per-lane B fragment base: wT[(wave*64 + m16)][quad*8]
    const unsigned short* bp = wT + (size_t)(wave * 64 + m16) * K + quad * 8;

    // ---- prologue: issue step-0 x and first B subtile, quant, stage As[0] ----
    frag8 bcur[4];
    {
        float4 a0 = *(const float4*)(xp + 0);
        float4 b0 = *(const float4*)(xp + 4);
        float4 a1 = *(const float4*)(xp + 64);
        float4 b1 = *(const float4*)(xp + 68);
        #pragma unroll
        for (int nt = 0; nt < 4; ++nt)
            bcur[nt] = *(const frag8*)(bp + (size_t)nt * 16 * K);
        *(uint4*)&As[0][arow * LDA + acol]      = quant8(a0, b0);
        *(uint4*)&As[0][arow * LDA + acol + 64] = quant8(a1, b1);
    }
    __syncthreads();

    #pragma unroll
    for (int kt = 0; kt < NSTEP; ++kt) {
        const int cur = kt & 1;
        // issue next step's x loads early (latency hides under this step's MFMAs)
        float4 a0, b0, a1, b1;
        if (kt + 1 < NSTEP) {
            const float* xn = xp + (kt + 1) * BK;
            a0 = *(const float4*)(xn + 0);
            b0 = *(const float4*)(xn + 4);
            a1 = *(const float4*)(xn + 64);
            b1 = *(const float4*)(xn + 68);
        }
        #pragma unroll
        for (int kk = 0; kk < 4; ++kk) {
            const int gk = kt * 4 + kk + 1;     // next k-subtile (global index)
            frag8 bnext[4];
            if (gk < 16) {                      // prefetch next B subtile (L2)
                #pragma unroll
                for (int nt = 0; nt < 4; ++nt)
                    bnext[nt] = *(const frag8*)(bp + (size_t)nt * 16 * K + gk * 32);
            }
            frag8 af[4];
            #pragma unroll
            for (int mt = 0; mt < 4; ++mt)
                af[mt] = *(const frag8*)&As[cur][(mt * 16 + m16) * LDA + kk * 32 + quad * 8];
            #pragma unroll
            for (int nt = 0; nt < 4; ++nt)
                #pragma unroll
                for (int mt = 0; mt < 4; ++mt)
                    acc[mt][nt] = __builtin_amdgcn_mfma_f32_16x16x32_bf16(
                        af[mt], bcur[nt], acc[mt][nt], 0, 0, 0);
            if (gk < 16) {
                #pragma unroll
                for (int nt = 0; nt < 4; ++nt) bcur[nt] = bnext[nt];
            }
        }
        if (kt + 1 < NSTEP) {
            // write-late: x arrived long ago; B prefetches stay in flight past this wait
            *(uint4*)&As[cur ^ 1][arow * LDA + acol]      = quant8(a0, b0);
            *(uint4*)&As[cur ^ 1][arow * LDA + acol + 64] = quant8(a1, b1);
            __syncthreads();
        }
    }

    // epilogue: C layout col=lane&15, row=quad*4+reg (m89/m91-verified).
    // nontemporal stores: out is write-once, keep it from evicting hot wT in L2.
    #pragma unroll
    for (int nt = 0; nt < 4; ++nt) {
        int col = wave * 64 + nt * 16 + m16;
        float ds = dscale[col];
        float bv = bias[col];
        #pragma unroll
        for (int mt = 0; mt < 4; ++mt) {
            int row = blk * BM + mt * 16 + quad * 4;
            #pragma unroll
            for (int r = 0; r < 4; ++r)
                __builtin_nontemporal_store(acc[mt][nt][r] * ds + bv,
                                            &out[(size_t)(row + r) * F + col]);
        }
    }
}

extern "C" void kernel_launch(void* const* d_in, const int* in_sizes, int n_in,
                              void* d_out, int out_size, void* d_ws, size_t ws_size,
                              hipStream_t stream) {
    const float* x    = (const float*)d_in[0];
    const float* kern = (const float*)d_in[1];
    const float* bias = (const float*)d_in[2];
    float* out = (float*)d_out;

    unsigned short* wT = (unsigned short*)d_ws;                       // 512*512 bf16 = 512 KB
    float* dscale = (float*)((char*)d_ws + (size_t)K * F * sizeof(unsigned short));

    quant_w_kernel<<<F / 32, 512, 0, stream>>>(kern, wT, dscale);
    gemm_kernel<<<N / 64, 512, 0, stream>>>(x, wT, dscale, bias, out);
}